// Round 1
// baseline (2003.485 us; speedup 1.0000x reference)
//
#include <hip/hip_runtime.h>
#include <hip/hip_bf16.h>
#include <math.h>

#define BLK 256

// ---------------- degree kernels ----------------
__global__ void fill_ones(float* __restrict__ p, int n) {
    int i = blockIdx.x * BLK + threadIdx.x;
    if (i < n) p[i] = 1.0f;
}

__global__ void count_deg(const int* __restrict__ dst, float* __restrict__ deg, int E_) {
    int e = blockIdx.x * BLK + threadIdx.x;
    if (e < E_) atomicAdd(&deg[dst[e]], 1.0f);
}

__global__ void rsqrt_inplace(float* __restrict__ p, int n) {
    int i = blockIdx.x * BLK + threadIdx.x;
    if (i < n) p[i] = rsqrtf(p[i]);
}

// ---------------- GEMM: h = x @ W, H=16 ----------------
// block = 256 threads -> 16 rows x 16 cols; x tile + W staged in LDS.
template <int F>
__global__ void gemm16(const float* __restrict__ x, const float* __restrict__ W,
                       float* __restrict__ out, int n) {
    __shared__ float Ws[F * 16];
    __shared__ float xs[16 * F];
    int tid = threadIdx.x;
    for (int i = tid; i < F * 16; i += BLK) Ws[i] = W[i];
    int row0 = blockIdx.x * 16;
    for (int i = tid; i < 16 * F; i += BLK) {
        int r = i / F, c = i - r * F;
        int gr = row0 + r;
        xs[i] = (gr < n) ? x[(long long)gr * F + c] : 0.0f;
    }
    __syncthreads();
    int r = tid >> 4, c = tid & 15;
    float acc = 0.0f;
#pragma unroll 8
    for (int f = 0; f < F; ++f) acc += xs[r * F + f] * Ws[f * 16 + c];
    int gr = row0 + r;
    if (gr < n) out[gr * 16 + c] = acc;
}

// ---------------- init: out = bias + selfloop + optional skips (H=16) ----------------
// add1 != null: out += relu(add1) + add1 ; add2 != null: out += add2
__global__ void init_out16(float* __restrict__ out, const float* __restrict__ hlin,
                           const float* __restrict__ dinv, const float* __restrict__ bias,
                           const float* __restrict__ add1, const float* __restrict__ add2,
                           int n) {
    int i = blockIdx.x * BLK + threadIdx.x;
    if (i >= n * 16) return;
    int node = i >> 4, k = i & 15;
    float d = dinv[node];
    float v = bias[k] + hlin[i] * d * d;
    if (add1) { float a = add1[i]; v += fmaxf(a, 0.0f) + a; }
    if (add2) v += add2[i];
    out[i] = v;
}

__global__ void init_out10(float* __restrict__ out, const float* __restrict__ hlin,
                           const float* __restrict__ dinv, const float* __restrict__ bias,
                           int n) {
    int i = blockIdx.x * BLK + threadIdx.x;
    if (i >= n * 10) return;
    int node = i / 10, k = i - node * 10;
    float d = dinv[node];
    out[i] = bias[k] + hlin[i] * d * d;
}

// ---------------- edge aggregation: out[dst] += h[src]*dinv[src]*dinv[dst] ----------------
template <int H>
__global__ void edge_agg(const int* __restrict__ ei, const float* __restrict__ dinv,
                         const float* __restrict__ hlin, float* __restrict__ out, int E_) {
    int t = blockIdx.x * BLK + threadIdx.x;
    if (t >= E_ * H) return;
    int e = t / H, k = t - e * H;
    int s = ei[e];
    int d = ei[E_ + e];
    float coef = dinv[s] * dinv[d];
    atomicAdd(&out[d * H + k], hlin[s * H + k] * coef);
}

// ---------------- final GEMM: relu(h_f) @ We (16 -> 10) ----------------
__global__ void gemm_final(const float* __restrict__ hf, const float* __restrict__ We,
                           float* __restrict__ out, int n) {
    __shared__ float Ws[160];
    if (threadIdx.x < 160) Ws[threadIdx.x] = We[threadIdx.x];
    __syncthreads();
    int t = blockIdx.x * BLK + threadIdx.x;
    if (t >= n * 10) return;
    int i = t / 10, j = t - i * 10;
    float acc = 0.0f;
#pragma unroll
    for (int k = 0; k < 16; ++k) acc += fmaxf(hf[i * 16 + k], 0.0f) * Ws[k * 10 + j];
    out[t] = acc;
}

// ---------------- log_softmax over 10 cols ----------------
__global__ void logsoftmax10(const float* __restrict__ logits, float* __restrict__ out, int n) {
    int i = blockIdx.x * BLK + threadIdx.x;
    if (i >= n) return;
    float v[10];
    float m = -INFINITY;
#pragma unroll
    for (int j = 0; j < 10; ++j) { v[j] = logits[i * 10 + j]; m = fmaxf(m, v[j]); }
    float s = 0.0f;
#pragma unroll
    for (int j = 0; j < 10; ++j) s += expf(v[j] - m);
    float ls = logf(s);
#pragma unroll
    for (int j = 0; j < 10; ++j) out[i * 10 + j] = v[j] - m - ls;
}

extern "C" void kernel_launch(void* const* d_in, const int* in_sizes, int n_in,
                              void* d_out, int out_size, void* d_ws, size_t ws_size,
                              hipStream_t stream) {
    const float* x_parent = (const float*)d_in[0];
    const float* x_child1 = (const float*)d_in[1];
    const float* x_child2 = (const float*)d_in[2];
    const float* x_fd     = (const float*)d_in[3];
    const int* e_p   = (const int*)d_in[4];
    const int* e_c1  = (const int*)d_in[5];
    const int* e_c2  = (const int*)d_in[6];
    const int* e_fd  = (const int*)d_in[7];
    const float* W1 = (const float*)d_in[8];
    const float* b1 = (const float*)d_in[9];
    const float* W2 = (const float*)d_in[10];
    const float* b2 = (const float*)d_in[11];
    const float* W3 = (const float*)d_in[12];
    const float* b3 = (const float*)d_in[13];
    const float* We = (const float*)d_in[14];
    const float* be = (const float*)d_in[15];

    const int n  = in_sizes[0] / 128;   // 100000
    const int E_ = in_sizes[4] / 2;     // 3200000

    float* ws = (float*)d_ws;
    float* dinv_p  = ws;                 // n
    float* dinv_c1 = ws + (size_t)n;     // n
    float* dinv_c2 = ws + (size_t)2 * n; // n
    float* dinv_fd = ws + (size_t)3 * n; // n
    float* hlin = ws + (size_t)4 * n;    // 16n (also reused for final hlin 10n)
    float* hp   = hlin + (size_t)16 * n; // 16n
    float* hc1  = hp   + (size_t)16 * n;
    float* hc2  = hc1  + (size_t)16 * n;
    float* hf   = hc2  + (size_t)16 * n;
    float* logits = hf + (size_t)16 * n; // 10n

    const int gN16 = (n * 16 + BLK - 1) / BLK;
    const int gN10 = (n * 10 + BLK - 1) / BLK;
    const int gE   = (E_ + BLK - 1) / BLK;
    const int gE16 = (E_ * 16 + BLK - 1) / BLK;
    const int gE10 = (E_ * 10 + BLK - 1) / BLK;
    const int g4N  = (4 * n + BLK - 1) / BLK;
    const int gRow = (n + 15) / 16;

    // degrees (with self loop) -> dinv, for all 4 edge lists
    fill_ones<<<g4N, BLK, 0, stream>>>(dinv_p, 4 * n);
    count_deg<<<gE, BLK, 0, stream>>>(e_p  + E_, dinv_p,  E_);
    count_deg<<<gE, BLK, 0, stream>>>(e_c1 + E_, dinv_c1, E_);
    count_deg<<<gE, BLK, 0, stream>>>(e_c2 + E_, dinv_c2, E_);
    count_deg<<<gE, BLK, 0, stream>>>(e_fd + E_, dinv_fd, E_);
    rsqrt_inplace<<<g4N, BLK, 0, stream>>>(dinv_p, 4 * n);

    // L1: h_parent = conv(x_parent, e_p, W1, b1)
    gemm16<128><<<gRow, BLK, 0, stream>>>(x_parent, W1, hlin, n);
    init_out16<<<gN16, BLK, 0, stream>>>(hp, hlin, dinv_p, b1, nullptr, nullptr, n);
    edge_agg<16><<<gE16, BLK, 0, stream>>>(e_p, dinv_p, hlin, hp, E_);

    // L2: h_c1 = conv(x_child1, e_c1, W2, b2) + relu(hp) + hp
    gemm16<129><<<gRow, BLK, 0, stream>>>(x_child1, W2, hlin, n);
    init_out16<<<gN16, BLK, 0, stream>>>(hc1, hlin, dinv_c1, b2, hp, nullptr, n);
    edge_agg<16><<<gE16, BLK, 0, stream>>>(e_c1, dinv_c1, hlin, hc1, E_);

    // L3: h_c2 = conv(x_child2, e_c2, W3, b3) + relu(hc1) + hc1
    gemm16<130><<<gRow, BLK, 0, stream>>>(x_child2, W3, hlin, n);
    init_out16<<<gN16, BLK, 0, stream>>>(hc2, hlin, dinv_c2, b3, hc1, nullptr, n);
    edge_agg<16><<<gE16, BLK, 0, stream>>>(e_c2, dinv_c2, hlin, hc2, E_);

    // L4: h_f = conv(x_fd, e_fd, W2, b2) + relu(hc2) + hc1 + hc2
    gemm16<129><<<gRow, BLK, 0, stream>>>(x_fd, W2, hlin, n);
    init_out16<<<gN16, BLK, 0, stream>>>(hf, hlin, dinv_fd, b2, hc2, hc1, n);
    edge_agg<16><<<gE16, BLK, 0, stream>>>(e_fd, dinv_fd, hlin, hf, E_);

    // L5: out = conv(relu(h_f), e_fd, We, be) -> log_softmax
    gemm_final<<<gN10, BLK, 0, stream>>>(hf, We, hlin, n);  // hlin reused as [n,10]
    init_out10<<<gN10, BLK, 0, stream>>>(logits, hlin, dinv_fd, be, n);
    edge_agg<10><<<gE10, BLK, 0, stream>>>(e_fd, dinv_fd, hlin, logits, E_);
    logsoftmax10<<<gN10, BLK, 0, stream>>>(logits, (float*)d_out, n);
}